// Round 10
// baseline (269.714 us; speedup 1.0000x reference)
//
#include <hip/hip_runtime.h>
#include <hip/hip_fp16.h>

// GCN 3-layer fused pipeline for MI355X.
// Bucketed CSR build (bin -> bucket-hist -> scan -> local scatter), then per
// layer: fp16 MFMA GEMM (W in LDS, dinv-scaled fp16 H epilogue) -> pull-mode
// aggregation over fp16 H (8-deep gather pipeline) with fused BN/LeakyReLU.

#define LRELU_SLOPE 0.1f
#define BN_EPS 1e-5f
#define BCAP 20480   // max edges per 1024-node bucket (mean 16384, 32 sigma)

typedef _Float16 half8 __attribute__((ext_vector_type(8)));
typedef float f32x4 __attribute__((ext_vector_type(4)));

// One prep kernel: W transposes (fp16, padded stride 136), BN scale/shift
// folding, bucket-cursor init.
__global__ void prep_all(const float* __restrict__ W1, const float* __restrict__ W2,
                         const float* __restrict__ W3, _Float16* __restrict__ W1t,
                         _Float16* __restrict__ W2t, _Float16* __restrict__ W3t,
                         const float* __restrict__ b1, const float* __restrict__ g1,
                         const float* __restrict__ be1, const float* __restrict__ m1,
                         const float* __restrict__ v1,
                         const float* __restrict__ b2, const float* __restrict__ g2,
                         const float* __restrict__ be2, const float* __restrict__ m2,
                         const float* __restrict__ v2,
                         const float* __restrict__ b3,
                         float* __restrict__ sc1, float* __restrict__ sh1,
                         float* __restrict__ sc2, float* __restrict__ sh2,
                         float* __restrict__ sc3, float* __restrict__ sh3,
                         int* __restrict__ bcur) {
    int i = blockIdx.x * 256 + threadIdx.x;
    if (i < 16384) {
        int k = i >> 7, c = i & 127;
        W1t[c * 136 + k] = (_Float16)W1[i];
    } else if (i < 32768) {
        int j = i - 16384;
        int k = j >> 7, c = j & 127;
        W2t[c * 136 + k] = (_Float16)W2[j];
    } else if (i < 40960) {
        int j = i - 32768;
        int k = j >> 6, c = j & 63;
        W3t[c * 136 + k] = (_Float16)W3[j];
    } else if (i < 41088) {
        int f = i - 40960;
        float s = g1[f] * rsqrtf(v1[f] + BN_EPS);
        sc1[f] = s;
        sh1[f] = (b1[f] - m1[f]) * s + be1[f];
    } else if (i < 41216) {
        int f = i - 41088;
        float s = g2[f] * rsqrtf(v2[f] + BN_EPS);
        sc2[f] = s;
        sh2[f] = (b2[f] - m2[f]) * s + be2[f];
    } else if (i < 41280) {
        int f = i - 41216;
        sc3[f] = 1.0f;
        sh3[f] = b3[f];
    } else if (i < 41344) {
        bcur[i - 41280] = (i - 41280) * BCAP;
    }
}

// Phase A: bin edges into per-bucket regions as packed (src<<32|dst) pairs.
__global__ __launch_bounds__(256) void bin_pass(const int* __restrict__ src,
                                                const int* __restrict__ dst, int E,
                                                int* __restrict__ bcur,
                                                unsigned long long* __restrict__ pairs) {
    __shared__ int sd[1664], ss[1664];
    __shared__ int lcur[64];
    const int tid = threadIdx.x;
    const int chunk = (E + gridDim.x - 1) / gridDim.x;  // 1563 at E=800k, 512 blocks
    const int e0 = blockIdx.x * chunk;
    const int ecnt = min(chunk, E - e0);
    for (int j = tid; j < ecnt; j += 256) {
        sd[j] = dst[e0 + j];
        ss[j] = src[e0 + j];
    }
    if (tid < 64) lcur[tid] = 0;
    __syncthreads();
    for (int j = tid; j < ecnt; j += 256) atomicAdd(&lcur[sd[j] >> 10], 1);
    __syncthreads();
    if (tid < 64) lcur[tid] = atomicAdd(&bcur[tid], lcur[tid]);  // base into lcur
    __syncthreads();
    for (int j = tid; j < ecnt; j += 256) {
        const int b = sd[j] >> 10;
        const int pos = atomicAdd(&lcur[b], 1);
        pairs[pos] = ((unsigned long long)(unsigned)ss[j] << 32) | (unsigned)sd[j];
    }
}

// Per-bucket degree histogram (LDS, no global atomics) -> dense cnt write.
__global__ __launch_bounds__(512) void hist_bucket(const unsigned long long* __restrict__ pairs,
                                                   const int* __restrict__ bcur,
                                                   int* __restrict__ cnt, int N) {
    __shared__ int h[1024];
    const int b = blockIdx.x;
    const int base = b << 10;
    const int nn = min(1024, N - base);
    const int cntb = bcur[b] - b * BCAP;
    for (int i = threadIdx.x; i < 1024; i += 512) h[i] = 0;
    __syncthreads();
    const unsigned long long* pb = pairs + (size_t)b * BCAP;
    for (int j = threadIdx.x; j < cntb; j += 512) {
        const int d = (int)(pb[j] & 0xffffffffull);
        atomicAdd(&h[d - base], 1);
    }
    __syncthreads();
    for (int i = threadIdx.x; i < nn; i += 512) cnt[base + i] = h[i];
}

// Block-level inclusive scan (256 elements per block) + per-block totals.
__global__ void scan1(const int* __restrict__ cnt, int* __restrict__ incl,
                      int* __restrict__ part, int n) {
    __shared__ int s[256];
    int tid = threadIdx.x;
    int gid = blockIdx.x * 256 + tid;
    int v = (gid < n) ? cnt[gid] : 0;
    s[tid] = v;
    __syncthreads();
    for (int off = 1; off < 256; off <<= 1) {
        int t = (tid >= off) ? s[tid - off] : 0;
        __syncthreads();
        s[tid] += t;
        __syncthreads();
    }
    if (gid < n) incl[gid] = s[tid];
    if (tid == 255) part[blockIdx.x] = s[255];
}

// Merged scan2+scan3: each block reduces part[0..blockIdx) itself, then
// writes row_ptr + dinv. nb_n <= ~256 so the redundant reduce is trivial.
__global__ void scan23(const int* __restrict__ cnt, const int* __restrict__ incl,
                       const int* __restrict__ part, int* __restrict__ row_ptr,
                       float* __restrict__ dinv, int n, int E) {
    __shared__ int red[256];
    const int tid = threadIdx.x;
    int acc = 0;
    for (int i = tid; i < blockIdx.x; i += 256) acc += part[i];
    red[tid] = acc;
    __syncthreads();
    for (int off = 128; off > 0; off >>= 1) {
        if (tid < off) red[tid] += red[tid + off];
        __syncthreads();
    }
    const int pof = red[0];
    const int gid = blockIdx.x * 256 + tid;
    if (gid < n) {
        int c = cnt[gid];
        row_ptr[gid] = incl[gid] - c + pof;
        dinv[gid] = rsqrtf(1.0f + (float)c);
    }
    if (gid == 0) row_ptr[n] = E;
}

// Phase B: per-bucket local CSR scatter with LDS cursors.
__global__ __launch_bounds__(512) void build_csr(const unsigned long long* __restrict__ pairs,
                                                 const int* __restrict__ bcur,
                                                 const int* __restrict__ row_ptr,
                                                 int* __restrict__ ssrc_g, int N) {
    __shared__ int cur[1024];
    const int b = blockIdx.x;
    const int base = b << 10;
    const int nn = min(1024, N - base);
    const int cntb = bcur[b] - b * BCAP;
    for (int i = threadIdx.x; i < nn; i += 512) cur[i] = row_ptr[base + i];
    __syncthreads();
    const unsigned long long* pb = pairs + (size_t)b * BCAP;
    for (int j = threadIdx.x; j < cntb; j += 512) {
        const unsigned long long p = pb[j];
        const int d = (int)(p & 0xffffffffull);
        const int s = (int)(p >> 32);
        const int pos = atomicAdd(&cur[d - base], 1);
        ssrc_g[pos] = s;
    }
}

// H[r][c] = fp16( (sum_k A[r][k] * W[k][c]) * dinv[r] ),  K fixed at 128.
template <int NC, bool AF32>
__global__ __launch_bounds__(256) void gemm_mfma(const void* __restrict__ Ain,
                                                 const _Float16* __restrict__ Wt,
                                                 const float* __restrict__ dinv,
                                                 __half* __restrict__ H, int nrows) {
    constexpr int NT = NC / 16;                    // N fragments per wave
    constexpr int SPH = (NC == 128) ? 136 : 88;    // Hl padded row (halves)
    __shared__ _Float16 smem[NC * 136];

    const int tid = threadIdx.x;
    const int row0 = blockIdx.x * 64;

    {
        const uint4* src = reinterpret_cast<const uint4*>(Wt);
        uint4* dst = reinterpret_cast<uint4*>(smem);
        for (int i = tid; i < NC * 17; i += 256) dst[i] = src[i];
    }
    __syncthreads();

    const int w = tid >> 6;
    const int lane = tid & 63;
    const int l15 = lane & 15;
    const int kg = lane >> 4;  // 0..3

    int ar = row0 + w * 16 + l15;
    if (ar > nrows - 1) ar = nrows - 1;
    half8 a[4];
#pragma unroll
    for (int ks = 0; ks < 4; ++ks) {
        const int cb = ks * 32 + kg * 8;
        if constexpr (AF32) {
            const float* Xf = (const float*)Ain;
            const float4 x0 = *reinterpret_cast<const float4*>(&Xf[(size_t)ar * 128 + cb]);
            const float4 x1 = *reinterpret_cast<const float4*>(&Xf[(size_t)ar * 128 + cb + 4]);
            half8 av;
            av[0] = (_Float16)x0.x; av[1] = (_Float16)x0.y;
            av[2] = (_Float16)x0.z; av[3] = (_Float16)x0.w;
            av[4] = (_Float16)x1.x; av[5] = (_Float16)x1.y;
            av[6] = (_Float16)x1.z; av[7] = (_Float16)x1.w;
            a[ks] = av;
        } else {
            const __half* Xh = (const __half*)Ain;
            a[ks] = *reinterpret_cast<const half8*>(&Xh[(size_t)ar * 128 + cb]);
        }
    }

    f32x4 acc[NT];
#pragma unroll
    for (int nt = 0; nt < NT; ++nt) acc[nt] = {0.f, 0.f, 0.f, 0.f};

#pragma unroll
    for (int nt = 0; nt < NT; ++nt) {
        const int c = nt * 16 + l15;
#pragma unroll
        for (int ks = 0; ks < 4; ++ks) {
            const half8 b = *reinterpret_cast<const half8*>(&smem[c * 136 + ks * 32 + kg * 8]);
            acc[nt] = __builtin_amdgcn_mfma_f32_16x16x32_f16(a[ks], b, acc[nt], 0, 0, 0);
        }
    }

    __syncthreads();  // all B-reads done; reuse smem as Hl[64][SPH]

    float dv[4];
#pragma unroll
    for (int r = 0; r < 4; ++r) {
        int gr = row0 + w * 16 + kg * 4 + r;
        if (gr > nrows - 1) gr = nrows - 1;
        dv[r] = dinv[gr];
    }
    _Float16* Hl = smem;
#pragma unroll
    for (int nt = 0; nt < NT; ++nt) {
#pragma unroll
        for (int r = 0; r < 4; ++r) {
            Hl[(w * 16 + kg * 4 + r) * SPH + nt * 16 + l15] = (_Float16)(acc[nt][r] * dv[r]);
        }
    }
    __syncthreads();

    constexpr int CG = NC / 8;
    for (int i = tid; i < 64 * CG; i += 256) {
        const int row = i / CG, cg = i % CG;
        const int gr = row0 + row;
        if (gr < nrows) {
            *reinterpret_cast<uint4*>(&H[(size_t)gr * NC + cg * 8]) =
                *reinterpret_cast<const uint4*>(&Hl[row * SPH + cg * 8]);
        }
    }
}

__device__ __forceinline__ float2 u2f2(unsigned u) {
    __half2 h;
    *reinterpret_cast<unsigned*>(&h) = u;
    return __half22float2(h);
}

// out[n][f] = act( (dinv[n]*(H[n][f] + sum_{e in row n} H[ssrc[e]][f])) * sc[f] + sh[f] )
// 32 threads/node, 8 nodes/block, 8-deep gather pipeline.
template <int NC, bool ACT, bool HOUT>
__global__ __launch_bounds__(256) void agg_h(
    const __half* __restrict__ H, const int* __restrict__ row_ptr,
    const int* __restrict__ ssrc, const float* __restrict__ dinv,
    const float* __restrict__ sc, const float* __restrict__ sh,
    void* __restrict__ out, int n) {
    constexpr int FPT = NC / 32;
    const int tid = threadIdx.x;
    const int node = blockIdx.x * 8 + (tid >> 5);
    const int lane = tid & 31;
    const int f0 = lane * FPT;
    if (node >= n) return;

    const int e0 = row_ptr[node];
    const int e1 = row_ptr[node + 1];

    if constexpr (FPT == 4) {
        uint2 su = *reinterpret_cast<const uint2*>(&H[(size_t)node * NC + f0]);
        float2 slo = u2f2(su.x), shi = u2f2(su.y);
        float4 A0 = {slo.x, slo.y, shi.x, shi.y};
        float4 A1 = {0, 0, 0, 0}, A2 = {0, 0, 0, 0}, A3 = {0, 0, 0, 0};
        int e = e0;
        for (; e + 7 < e1; e += 8) {
            int s[8];
#pragma unroll
            for (int j = 0; j < 8; ++j) s[j] = ssrc[e + j];
            uint2 u[8];
#pragma unroll
            for (int j = 0; j < 8; ++j)
                u[j] = *reinterpret_cast<const uint2*>(&H[(size_t)s[j] * NC + f0]);
#pragma unroll
            for (int j = 0; j < 8; ++j) {
                float2 l = u2f2(u[j].x), h = u2f2(u[j].y);
                float4& A = (j & 3) == 0 ? A0 : (j & 3) == 1 ? A1 : (j & 3) == 2 ? A2 : A3;
                A.x += l.x; A.y += l.y; A.z += h.x; A.w += h.y;
            }
        }
        for (; e < e1; ++e) {
            const uint2 u = *reinterpret_cast<const uint2*>(&H[(size_t)ssrc[e] * NC + f0]);
            float2 l = u2f2(u.x), h = u2f2(u.y);
            A1.x += l.x; A1.y += l.y; A1.z += h.x; A1.w += h.y;
        }
        float4 acc;
        acc.x = (A0.x + A1.x) + (A2.x + A3.x);
        acc.y = (A0.y + A1.y) + (A2.y + A3.y);
        acc.z = (A0.z + A1.z) + (A2.z + A3.z);
        acc.w = (A0.w + A1.w) + (A2.w + A3.w);
        const float dn = dinv[node];
        const float4 scv = *reinterpret_cast<const float4*>(&sc[f0]);
        const float4 shv = *reinterpret_cast<const float4*>(&sh[f0]);
        float o[4];
        o[0] = fmaf(acc.x * dn, scv.x, shv.x);
        o[1] = fmaf(acc.y * dn, scv.y, shv.y);
        o[2] = fmaf(acc.z * dn, scv.z, shv.z);
        o[3] = fmaf(acc.w * dn, scv.w, shv.w);
        if constexpr (ACT) {
#pragma unroll
            for (int j = 0; j < 4; ++j) o[j] = o[j] > 0.f ? o[j] : LRELU_SLOPE * o[j];
        }
        if constexpr (HOUT) {
            __half2 p0 = __floats2half2_rn(o[0], o[1]);
            __half2 p1 = __floats2half2_rn(o[2], o[3]);
            uint2 st;
            st.x = *reinterpret_cast<unsigned*>(&p0);
            st.y = *reinterpret_cast<unsigned*>(&p1);
            *reinterpret_cast<uint2*>(&((__half*)out)[(size_t)node * NC + f0]) = st;
        } else {
            float4 ov = {o[0], o[1], o[2], o[3]};
            *reinterpret_cast<float4*>(&((float*)out)[(size_t)node * NC + f0]) = ov;
        }
    } else {
        unsigned su = *reinterpret_cast<const unsigned*>(&H[(size_t)node * NC + f0]);
        float2 A0 = u2f2(su);
        float2 A1 = {0, 0}, A2 = {0, 0}, A3 = {0, 0};
        int e = e0;
        for (; e + 7 < e1; e += 8) {
            int s[8];
#pragma unroll
            for (int j = 0; j < 8; ++j) s[j] = ssrc[e + j];
            unsigned u[8];
#pragma unroll
            for (int j = 0; j < 8; ++j)
                u[j] = *reinterpret_cast<const unsigned*>(&H[(size_t)s[j] * NC + f0]);
#pragma unroll
            for (int j = 0; j < 8; ++j) {
                float2 f = u2f2(u[j]);
                float2& A = (j & 3) == 0 ? A0 : (j & 3) == 1 ? A1 : (j & 3) == 2 ? A2 : A3;
                A.x += f.x; A.y += f.y;
            }
        }
        for (; e < e1; ++e) {
            float2 f = u2f2(*reinterpret_cast<const unsigned*>(&H[(size_t)ssrc[e] * NC + f0]));
            A1.x += f.x; A1.y += f.y;
        }
        float2 acc;
        acc.x = (A0.x + A1.x) + (A2.x + A3.x);
        acc.y = (A0.y + A1.y) + (A2.y + A3.y);
        const float dn = dinv[node];
        const float2 scv = *reinterpret_cast<const float2*>(&sc[f0]);
        const float2 shv = *reinterpret_cast<const float2*>(&sh[f0]);
        float o0 = fmaf(acc.x * dn, scv.x, shv.x);
        float o1 = fmaf(acc.y * dn, scv.y, shv.y);
        if constexpr (ACT) {
            o0 = o0 > 0.f ? o0 : LRELU_SLOPE * o0;
            o1 = o1 > 0.f ? o1 : LRELU_SLOPE * o1;
        }
        if constexpr (HOUT) {
            __half2 p0 = __floats2half2_rn(o0, o1);
            *reinterpret_cast<unsigned*>(&((__half*)out)[(size_t)node * NC + f0]) =
                *reinterpret_cast<unsigned*>(&p0);
        } else {
            float2 ov = {o0, o1};
            *reinterpret_cast<float2*>(&((float*)out)[(size_t)node * NC + f0]) = ov;
        }
    }
}

extern "C" void kernel_launch(void* const* d_in, const int* in_sizes, int n_in,
                              void* d_out, int out_size, void* d_ws, size_t ws_size,
                              hipStream_t stream) {
    const float* x  = (const float*)d_in[0];
    const int* ei   = (const int*)d_in[1];
    const float* W1 = (const float*)d_in[2];
    const float* b1 = (const float*)d_in[3];
    const float* g1 = (const float*)d_in[4];
    const float* be1= (const float*)d_in[5];
    const float* m1 = (const float*)d_in[6];
    const float* v1 = (const float*)d_in[7];
    const float* W2 = (const float*)d_in[8];
    const float* b2 = (const float*)d_in[9];
    const float* g2 = (const float*)d_in[10];
    const float* be2= (const float*)d_in[11];
    const float* m2 = (const float*)d_in[12];
    const float* v2 = (const float*)d_in[13];
    const float* W3 = (const float*)d_in[14];
    const float* b3 = (const float*)d_in[15];
    float* out = (float*)d_out;

    const int N = in_sizes[0] / 128;
    const int E = in_sizes[1] / 2;
    const int* srcIdx = ei;       // edge_index[0]
    const int* dstIdx = ei + E;   // edge_index[1]
    const int nbuck = (N + 1023) >> 10;  // 49

    char* p = (char*)d_ws;
    auto carve = [&](size_t bytes) -> void* {
        void* r = (void*)p;
        p += (bytes + 255) & ~(size_t)255;
        return r;
    };
    int* cnt       = (int*)carve((size_t)N * 4);
    int* incl      = (int*)carve((size_t)N * 4);
    int* part      = (int*)carve(1024);
    int* row_ptr   = (int*)carve((size_t)(N + 1) * 4);
    int* bcur      = (int*)carve(64 * 4);
    float* dinv    = (float*)carve((size_t)N * 4);
    int* ssrc      = (int*)carve((size_t)E * 4);
    unsigned long long* pairs = (unsigned long long*)carve((size_t)nbuck * BCAP * 8);
    __half* Hb     = (__half*)carve((size_t)N * 128 * 2);
    __half* Xb     = (__half*)carve((size_t)N * 128 * 2);
    _Float16* W1t  = (_Float16*)carve(128 * 136 * 2);
    _Float16* W2t  = (_Float16*)carve(128 * 136 * 2);
    _Float16* W3t  = (_Float16*)carve(64 * 136 * 2);
    float* sc1     = (float*)carve(128 * 4);
    float* sh1     = (float*)carve(128 * 4);
    float* sc2     = (float*)carve(128 * 4);
    float* sh2     = (float*)carve(128 * 4);
    float* sc3     = (float*)carve(64 * 4);
    float* sh3     = (float*)carve(64 * 4);
    (void)ws_size; (void)n_in; (void)out_size;

    const int nb_n = (N + 255) / 256;  // 196

    prep_all<<<162, 256, 0, stream>>>(W1, W2, W3, W1t, W2t, W3t,
                                      b1, g1, be1, m1, v1, b2, g2, be2, m2, v2, b3,
                                      sc1, sh1, sc2, sh2, sc3, sh3, bcur);
    bin_pass<<<512, 256, 0, stream>>>(srcIdx, dstIdx, E, bcur, pairs);
    hist_bucket<<<nbuck, 512, 0, stream>>>(pairs, bcur, cnt, N);
    scan1<<<nb_n, 256, 0, stream>>>(cnt, incl, part, N);
    scan23<<<nb_n, 256, 0, stream>>>(cnt, incl, part, row_ptr, dinv, N, E);
    build_csr<<<nbuck, 512, 0, stream>>>(pairs, bcur, row_ptr, ssrc, N);

    const int gb = (N + 63) / 64;
    const int ab = (N + 7) / 8;

    // Layer 1: x (f32) -> Hb -> Xb (fp16)
    gemm_mfma<128, true><<<gb, 256, 0, stream>>>(x, W1t, dinv, Hb, N);
    agg_h<128, true, true><<<ab, 256, 0, stream>>>(
        Hb, row_ptr, ssrc, dinv, sc1, sh1, Xb, N);

    // Layer 2: Xb (fp16) -> Hb -> Xb (fp16)
    gemm_mfma<128, false><<<gb, 256, 0, stream>>>(Xb, W2t, dinv, Hb, N);
    agg_h<128, true, true><<<ab, 256, 0, stream>>>(
        Hb, row_ptr, ssrc, dinv, sc2, sh2, Xb, N);

    // Layer 3: Xb (fp16) -> Hb (64 cols) -> out (f32)
    gemm_mfma<64, false><<<gb, 256, 0, stream>>>(Xb, W3t, dinv, Hb, N);
    agg_h<64, false, false><<<ab, 256, 0, stream>>>(
        Hb, row_ptr, ssrc, dinv, sc3, sh3, out, N);
}

// Round 14
// 261.757 us; speedup vs baseline: 1.0304x; 1.0304x over previous
//
#include <hip/hip_runtime.h>
#include <hip/hip_fp16.h>

// GCN 3-layer fused pipeline for MI355X.
// Bucketed CSR build (bin -> fused hist+scan -> fused prefix+scatter), then
// per layer: fp16 MFMA GEMM (W in LDS, dinv-scaled fp16 H epilogue) ->
// pull-mode aggregation over fp16 H with fused BN/LeakyReLU epilogue.
// Agg is at the ~2.5 TB/s beyond-L2 gather ceiling (R10 ablation: 8-deep
// pipeline neutral) -- this round trims CSR-build launches/traffic.

#define LRELU_SLOPE 0.1f
#define BN_EPS 1e-5f
#define BCAP 20480   // max edges per 1024-node bucket (mean 16384, ~32 sigma)

typedef _Float16 half8 __attribute__((ext_vector_type(8)));
typedef float f32x4 __attribute__((ext_vector_type(4)));

// One prep kernel: W transposes (fp16, padded stride 136), BN scale/shift
// folding, bucket-cursor init.
__global__ void prep_all(const float* __restrict__ W1, const float* __restrict__ W2,
                         const float* __restrict__ W3, _Float16* __restrict__ W1t,
                         _Float16* __restrict__ W2t, _Float16* __restrict__ W3t,
                         const float* __restrict__ b1, const float* __restrict__ g1,
                         const float* __restrict__ be1, const float* __restrict__ m1,
                         const float* __restrict__ v1,
                         const float* __restrict__ b2, const float* __restrict__ g2,
                         const float* __restrict__ be2, const float* __restrict__ m2,
                         const float* __restrict__ v2,
                         const float* __restrict__ b3,
                         float* __restrict__ sc1, float* __restrict__ sh1,
                         float* __restrict__ sc2, float* __restrict__ sh2,
                         float* __restrict__ sc3, float* __restrict__ sh3,
                         int* __restrict__ bcur) {
    int i = blockIdx.x * 256 + threadIdx.x;
    if (i < 16384) {
        int k = i >> 7, c = i & 127;
        W1t[c * 136 + k] = (_Float16)W1[i];
    } else if (i < 32768) {
        int j = i - 16384;
        int k = j >> 7, c = j & 127;
        W2t[c * 136 + k] = (_Float16)W2[j];
    } else if (i < 40960) {
        int j = i - 32768;
        int k = j >> 6, c = j & 63;
        W3t[c * 136 + k] = (_Float16)W3[j];
    } else if (i < 41088) {
        int f = i - 40960;
        float s = g1[f] * rsqrtf(v1[f] + BN_EPS);
        sc1[f] = s;
        sh1[f] = (b1[f] - m1[f]) * s + be1[f];
    } else if (i < 41216) {
        int f = i - 41088;
        float s = g2[f] * rsqrtf(v2[f] + BN_EPS);
        sc2[f] = s;
        sh2[f] = (b2[f] - m2[f]) * s + be2[f];
    } else if (i < 41280) {
        int f = i - 41216;
        sc3[f] = 1.0f;
        sh3[f] = b3[f];
    } else if (i < 41344) {
        bcur[i - 41280] = (i - 41280) * BCAP;
    }
}

// Phase A: bin edges into per-bucket regions as packed (src<<10 | dst&1023)
// uint32 (src < 50000 < 2^16, so 26 bits total -- fits).
__global__ __launch_bounds__(256) void bin_pass(const int* __restrict__ src,
                                                const int* __restrict__ dst, int E,
                                                int* __restrict__ bcur,
                                                unsigned* __restrict__ pairs) {
    __shared__ int sd[1664], ss[1664];
    __shared__ int lcur[64];
    const int tid = threadIdx.x;
    const int chunk = (E + gridDim.x - 1) / gridDim.x;  // 1563 at E=800k, 512 blocks
    const int e0 = blockIdx.x * chunk;
    const int ecnt = min(chunk, E - e0);
    for (int j = tid; j < ecnt; j += 256) {
        sd[j] = dst[e0 + j];
        ss[j] = src[e0 + j];
    }
    if (tid < 64) lcur[tid] = 0;
    __syncthreads();
    for (int j = tid; j < ecnt; j += 256) atomicAdd(&lcur[sd[j] >> 10], 1);
    __syncthreads();
    if (tid < 64) lcur[tid] = atomicAdd(&bcur[tid], lcur[tid]);  // base into lcur
    __syncthreads();
    for (int j = tid; j < ecnt; j += 256) {
        const int d = sd[j];
        const int pos = atomicAdd(&lcur[d >> 10], 1);
        pairs[pos] = ((unsigned)ss[j] << 10) | (unsigned)(d & 1023);
    }
}

// Fused per-bucket histogram + 1024-wide inclusive scan.
// Writes: row_ptr[base+i] = LOCAL exclusive prefix, dinv, part[bucket] = total.
__global__ __launch_bounds__(1024) void hist_scan(const unsigned* __restrict__ pairs,
                                                  const int* __restrict__ bcur,
                                                  int* __restrict__ row_ptr,
                                                  float* __restrict__ dinv,
                                                  int* __restrict__ part, int N) {
    __shared__ int h[1024];
    __shared__ int s[1024];
    const int b = blockIdx.x;
    const int tid = threadIdx.x;
    const int base = b << 10;
    const int nn = min(1024, N - base);
    const int cntb = bcur[b] - b * BCAP;
    h[tid] = 0;
    __syncthreads();
    const unsigned* pb = pairs + (size_t)b * BCAP;
    for (int j = tid; j < cntb; j += 1024) atomicAdd(&h[pb[j] & 1023u], 1);
    __syncthreads();
    const int v = h[tid];
    s[tid] = v;
    __syncthreads();
    for (int off = 1; off < 1024; off <<= 1) {
        int t = (tid >= off) ? s[tid - off] : 0;
        __syncthreads();
        s[tid] += t;
        __syncthreads();
    }
    if (tid < nn) {
        row_ptr[base + tid] = s[tid] - v;           // local exclusive
        dinv[base + tid] = rsqrtf(1.0f + (float)v);
    }
    if (tid == 1023) part[b] = s[1023];
}

// Fused bucket-prefix + CSR scatter: finalize row_ptr (+= prefix of part),
// then scatter srcs with LDS cursors (stores land in a ~3KB..80KB window).
__global__ __launch_bounds__(1024) void csr_scatter(const unsigned* __restrict__ pairs,
                                                    const int* __restrict__ bcur,
                                                    const int* __restrict__ part,
                                                    int* __restrict__ row_ptr,
                                                    int* __restrict__ ssrc_g,
                                                    int N, int E, int nbuck) {
    __shared__ int cur[1024];
    __shared__ int pofs;
    const int b = blockIdx.x;
    const int tid = threadIdx.x;
    const int base = b << 10;
    const int nn = min(1024, N - base);
    const int cntb = bcur[b] - b * BCAP;
    if (tid < 64) {  // wave 0 computes prefix of part[0..b) (b <= 48)
        int v = (tid < b) ? part[tid] : 0;
#pragma unroll
        for (int off = 32; off; off >>= 1) v += __shfl_down(v, off, 64);
        if (tid == 0) pofs = v;
    }
    __syncthreads();
    const int pof = pofs;
    if (tid < nn) {
        const int rp = row_ptr[base + tid] + pof;
        row_ptr[base + tid] = rp;
        cur[tid] = rp;
    }
    if (b == nbuck - 1 && tid == 0) row_ptr[N] = E;
    __syncthreads();
    const unsigned* pb = pairs + (size_t)b * BCAP;
    for (int j = tid; j < cntb; j += 1024) {
        const unsigned p = pb[j];
        const int pos = atomicAdd(&cur[p & 1023u], 1);
        ssrc_g[pos] = (int)(p >> 10);
    }
}

// H[r][c] = fp16( (sum_k A[r][k] * W[k][c]) * dinv[r] ),  K fixed at 128.
template <int NC, bool AF32>
__global__ __launch_bounds__(256) void gemm_mfma(const void* __restrict__ Ain,
                                                 const _Float16* __restrict__ Wt,
                                                 const float* __restrict__ dinv,
                                                 __half* __restrict__ H, int nrows) {
    constexpr int NT = NC / 16;                    // N fragments per wave
    constexpr int SPH = (NC == 128) ? 136 : 88;    // Hl padded row (halves)
    __shared__ _Float16 smem[NC * 136];

    const int tid = threadIdx.x;
    const int row0 = blockIdx.x * 64;

    {
        const uint4* src = reinterpret_cast<const uint4*>(Wt);
        uint4* dst = reinterpret_cast<uint4*>(smem);
        for (int i = tid; i < NC * 17; i += 256) dst[i] = src[i];
    }
    __syncthreads();

    const int w = tid >> 6;
    const int lane = tid & 63;
    const int l15 = lane & 15;
    const int kg = lane >> 4;  // 0..3

    int ar = row0 + w * 16 + l15;
    if (ar > nrows - 1) ar = nrows - 1;
    half8 a[4];
#pragma unroll
    for (int ks = 0; ks < 4; ++ks) {
        const int cb = ks * 32 + kg * 8;
        if constexpr (AF32) {
            const float* Xf = (const float*)Ain;
            const float4 x0 = *reinterpret_cast<const float4*>(&Xf[(size_t)ar * 128 + cb]);
            const float4 x1 = *reinterpret_cast<const float4*>(&Xf[(size_t)ar * 128 + cb + 4]);
            half8 av;
            av[0] = (_Float16)x0.x; av[1] = (_Float16)x0.y;
            av[2] = (_Float16)x0.z; av[3] = (_Float16)x0.w;
            av[4] = (_Float16)x1.x; av[5] = (_Float16)x1.y;
            av[6] = (_Float16)x1.z; av[7] = (_Float16)x1.w;
            a[ks] = av;
        } else {
            const __half* Xh = (const __half*)Ain;
            a[ks] = *reinterpret_cast<const half8*>(&Xh[(size_t)ar * 128 + cb]);
        }
    }

    f32x4 acc[NT];
#pragma unroll
    for (int nt = 0; nt < NT; ++nt) acc[nt] = {0.f, 0.f, 0.f, 0.f};

#pragma unroll
    for (int nt = 0; nt < NT; ++nt) {
        const int c = nt * 16 + l15;
#pragma unroll
        for (int ks = 0; ks < 4; ++ks) {
            const half8 b = *reinterpret_cast<const half8*>(&smem[c * 136 + ks * 32 + kg * 8]);
            acc[nt] = __builtin_amdgcn_mfma_f32_16x16x32_f16(a[ks], b, acc[nt], 0, 0, 0);
        }
    }

    __syncthreads();  // all B-reads done; reuse smem as Hl[64][SPH]

    float dv[4];
#pragma unroll
    for (int r = 0; r < 4; ++r) {
        int gr = row0 + w * 16 + kg * 4 + r;
        if (gr > nrows - 1) gr = nrows - 1;
        dv[r] = dinv[gr];
    }
    _Float16* Hl = smem;
#pragma unroll
    for (int nt = 0; nt < NT; ++nt) {
#pragma unroll
        for (int r = 0; r < 4; ++r) {
            Hl[(w * 16 + kg * 4 + r) * SPH + nt * 16 + l15] = (_Float16)(acc[nt][r] * dv[r]);
        }
    }
    __syncthreads();

    constexpr int CG = NC / 8;
    for (int i = tid; i < 64 * CG; i += 256) {
        const int row = i / CG, cg = i % CG;
        const int gr = row0 + row;
        if (gr < nrows) {
            *reinterpret_cast<uint4*>(&H[(size_t)gr * NC + cg * 8]) =
                *reinterpret_cast<const uint4*>(&Hl[row * SPH + cg * 8]);
        }
    }
}

__device__ __forceinline__ float2 u2f2(unsigned u) {
    __half2 h;
    *reinterpret_cast<unsigned*>(&h) = u;
    return __half22float2(h);
}

// out[n][f] = act( (dinv[n]*(H[n][f] + sum_{e in row n} H[ssrc[e]][f])) * sc[f] + sh[f] )
// 32 threads/node, 8 nodes/block, 8-deep gather pipeline.
template <int NC, bool ACT, bool HOUT>
__global__ __launch_bounds__(256) void agg_h(
    const __half* __restrict__ H, const int* __restrict__ row_ptr,
    const int* __restrict__ ssrc, const float* __restrict__ dinv,
    const float* __restrict__ sc, const float* __restrict__ sh,
    void* __restrict__ out, int n) {
    constexpr int FPT = NC / 32;
    const int tid = threadIdx.x;
    const int node = blockIdx.x * 8 + (tid >> 5);
    const int lane = tid & 31;
    const int f0 = lane * FPT;
    if (node >= n) return;

    const int e0 = row_ptr[node];
    const int e1 = row_ptr[node + 1];

    if constexpr (FPT == 4) {
        uint2 su = *reinterpret_cast<const uint2*>(&H[(size_t)node * NC + f0]);
        float2 slo = u2f2(su.x), shi = u2f2(su.y);
        float4 A0 = {slo.x, slo.y, shi.x, shi.y};
        float4 A1 = {0, 0, 0, 0}, A2 = {0, 0, 0, 0}, A3 = {0, 0, 0, 0};
        int e = e0;
        for (; e + 7 < e1; e += 8) {
            int s[8];
#pragma unroll
            for (int j = 0; j < 8; ++j) s[j] = ssrc[e + j];
            uint2 u[8];
#pragma unroll
            for (int j = 0; j < 8; ++j)
                u[j] = *reinterpret_cast<const uint2*>(&H[(size_t)s[j] * NC + f0]);
#pragma unroll
            for (int j = 0; j < 8; ++j) {
                float2 l = u2f2(u[j].x), h = u2f2(u[j].y);
                float4& A = (j & 3) == 0 ? A0 : (j & 3) == 1 ? A1 : (j & 3) == 2 ? A2 : A3;
                A.x += l.x; A.y += l.y; A.z += h.x; A.w += h.y;
            }
        }
        for (; e < e1; ++e) {
            const uint2 u = *reinterpret_cast<const uint2*>(&H[(size_t)ssrc[e] * NC + f0]);
            float2 l = u2f2(u.x), h = u2f2(u.y);
            A1.x += l.x; A1.y += l.y; A1.z += h.x; A1.w += h.y;
        }
        float4 acc;
        acc.x = (A0.x + A1.x) + (A2.x + A3.x);
        acc.y = (A0.y + A1.y) + (A2.y + A3.y);
        acc.z = (A0.z + A1.z) + (A2.z + A3.z);
        acc.w = (A0.w + A1.w) + (A2.w + A3.w);
        const float dn = dinv[node];
        const float4 scv = *reinterpret_cast<const float4*>(&sc[f0]);
        const float4 shv = *reinterpret_cast<const float4*>(&sh[f0]);
        float o[4];
        o[0] = fmaf(acc.x * dn, scv.x, shv.x);
        o[1] = fmaf(acc.y * dn, scv.y, shv.y);
        o[2] = fmaf(acc.z * dn, scv.z, shv.z);
        o[3] = fmaf(acc.w * dn, scv.w, shv.w);
        if constexpr (ACT) {
#pragma unroll
            for (int j = 0; j < 4; ++j) o[j] = o[j] > 0.f ? o[j] : LRELU_SLOPE * o[j];
        }
        if constexpr (HOUT) {
            __half2 p0 = __floats2half2_rn(o[0], o[1]);
            __half2 p1 = __floats2half2_rn(o[2], o[3]);
            uint2 st;
            st.x = *reinterpret_cast<unsigned*>(&p0);
            st.y = *reinterpret_cast<unsigned*>(&p1);
            *reinterpret_cast<uint2*>(&((__half*)out)[(size_t)node * NC + f0]) = st;
        } else {
            float4 ov = {o[0], o[1], o[2], o[3]};
            *reinterpret_cast<float4*>(&((float*)out)[(size_t)node * NC + f0]) = ov;
        }
    } else {
        unsigned su = *reinterpret_cast<const unsigned*>(&H[(size_t)node * NC + f0]);
        float2 A0 = u2f2(su);
        float2 A1 = {0, 0}, A2 = {0, 0}, A3 = {0, 0};
        int e = e0;
        for (; e + 7 < e1; e += 8) {
            int s[8];
#pragma unroll
            for (int j = 0; j < 8; ++j) s[j] = ssrc[e + j];
            unsigned u[8];
#pragma unroll
            for (int j = 0; j < 8; ++j)
                u[j] = *reinterpret_cast<const unsigned*>(&H[(size_t)s[j] * NC + f0]);
#pragma unroll
            for (int j = 0; j < 8; ++j) {
                float2 f = u2f2(u[j]);
                float2& A = (j & 3) == 0 ? A0 : (j & 3) == 1 ? A1 : (j & 3) == 2 ? A2 : A3;
                A.x += f.x; A.y += f.y;
            }
        }
        for (; e < e1; ++e) {
            float2 f = u2f2(*reinterpret_cast<const unsigned*>(&H[(size_t)ssrc[e] * NC + f0]));
            A1.x += f.x; A1.y += f.y;
        }
        float2 acc;
        acc.x = (A0.x + A1.x) + (A2.x + A3.x);
        acc.y = (A0.y + A1.y) + (A2.y + A3.y);
        const float dn = dinv[node];
        const float2 scv = *reinterpret_cast<const float2*>(&sc[f0]);
        const float2 shv = *reinterpret_cast<const float2*>(&sh[f0]);
        float o0 = fmaf(acc.x * dn, scv.x, shv.x);
        float o1 = fmaf(acc.y * dn, scv.y, shv.y);
        if constexpr (ACT) {
            o0 = o0 > 0.f ? o0 : LRELU_SLOPE * o0;
            o1 = o1 > 0.f ? o1 : LRELU_SLOPE * o1;
        }
        if constexpr (HOUT) {
            __half2 p0 = __floats2half2_rn(o0, o1);
            *reinterpret_cast<unsigned*>(&((__half*)out)[(size_t)node * NC + f0]) =
                *reinterpret_cast<unsigned*>(&p0);
        } else {
            float2 ov = {o0, o1};
            *reinterpret_cast<float2*>(&((float*)out)[(size_t)node * NC + f0]) = ov;
        }
    }
}

extern "C" void kernel_launch(void* const* d_in, const int* in_sizes, int n_in,
                              void* d_out, int out_size, void* d_ws, size_t ws_size,
                              hipStream_t stream) {
    const float* x  = (const float*)d_in[0];
    const int* ei   = (const int*)d_in[1];
    const float* W1 = (const float*)d_in[2];
    const float* b1 = (const float*)d_in[3];
    const float* g1 = (const float*)d_in[4];
    const float* be1= (const float*)d_in[5];
    const float* m1 = (const float*)d_in[6];
    const float* v1 = (const float*)d_in[7];
    const float* W2 = (const float*)d_in[8];
    const float* b2 = (const float*)d_in[9];
    const float* g2 = (const float*)d_in[10];
    const float* be2= (const float*)d_in[11];
    const float* m2 = (const float*)d_in[12];
    const float* v2 = (const float*)d_in[13];
    const float* W3 = (const float*)d_in[14];
    const float* b3 = (const float*)d_in[15];
    float* out = (float*)d_out;

    const int N = in_sizes[0] / 128;
    const int E = in_sizes[1] / 2;
    const int* srcIdx = ei;       // edge_index[0]
    const int* dstIdx = ei + E;   // edge_index[1]
    const int nbuck = (N + 1023) >> 10;  // 49

    char* p = (char*)d_ws;
    auto carve = [&](size_t bytes) -> void* {
        void* r = (void*)p;
        p += (bytes + 255) & ~(size_t)255;
        return r;
    };
    int* part      = (int*)carve(1024);
    int* row_ptr   = (int*)carve((size_t)(N + 1) * 4);
    int* bcur      = (int*)carve(64 * 4);
    float* dinv    = (float*)carve((size_t)N * 4);
    int* ssrc      = (int*)carve((size_t)E * 4);
    unsigned* pairs = (unsigned*)carve((size_t)nbuck * BCAP * 4);
    __half* Hb     = (__half*)carve((size_t)N * 128 * 2);
    __half* Xb     = (__half*)carve((size_t)N * 128 * 2);
    _Float16* W1t  = (_Float16*)carve(128 * 136 * 2);
    _Float16* W2t  = (_Float16*)carve(128 * 136 * 2);
    _Float16* W3t  = (_Float16*)carve(64 * 136 * 2);
    float* sc1     = (float*)carve(128 * 4);
    float* sh1     = (float*)carve(128 * 4);
    float* sc2     = (float*)carve(128 * 4);
    float* sh2     = (float*)carve(128 * 4);
    float* sc3     = (float*)carve(64 * 4);
    float* sh3     = (float*)carve(64 * 4);
    (void)ws_size; (void)n_in; (void)out_size;

    prep_all<<<162, 256, 0, stream>>>(W1, W2, W3, W1t, W2t, W3t,
                                      b1, g1, be1, m1, v1, b2, g2, be2, m2, v2, b3,
                                      sc1, sh1, sc2, sh2, sc3, sh3, bcur);
    bin_pass<<<512, 256, 0, stream>>>(srcIdx, dstIdx, E, bcur, pairs);
    hist_scan<<<nbuck, 1024, 0, stream>>>(pairs, bcur, row_ptr, dinv, part, N);
    csr_scatter<<<nbuck, 1024, 0, stream>>>(pairs, bcur, part, row_ptr, ssrc, N, E, nbuck);

    const int gb = (N + 63) / 64;
    const int ab = (N + 7) / 8;

    // Layer 1: x (f32) -> Hb -> Xb (fp16)
    gemm_mfma<128, true><<<gb, 256, 0, stream>>>(x, W1t, dinv, Hb, N);
    agg_h<128, true, true><<<ab, 256, 0, stream>>>(
        Hb, row_ptr, ssrc, dinv, sc1, sh1, Xb, N);

    // Layer 2: Xb (fp16) -> Hb -> Xb (fp16)
    gemm_mfma<128, false><<<gb, 256, 0, stream>>>(Xb, W2t, dinv, Hb, N);
    agg_h<128, true, true><<<ab, 256, 0, stream>>>(
        Hb, row_ptr, ssrc, dinv, sc2, sh2, Xb, N);

    // Layer 3: Xb (fp16) -> Hb (64 cols) -> out (f32)
    gemm_mfma<64, false><<<gb, 256, 0, stream>>>(Xb, W3t, dinv, Hb, N);
    agg_h<64, false, false><<<ab, 256, 0, stream>>>(
        Hb, row_ptr, ssrc, dinv, sc3, sh3, out, N);
}